// Round 7
// baseline (310.643 us; speedup 1.0000x reference)
//
#include <hip/hip_runtime.h>
#include <math.h>

typedef unsigned short ushort;
typedef unsigned int uint;
using half8   = __attribute__((ext_vector_type(8))) _Float16;
using short8  = __attribute__((ext_vector_type(8))) short;
using floatx4 = __attribute__((ext_vector_type(4))) float;

#define CCH   256
#define HWSZ  3136
#define NBAT  32
#define MCOLS (NBAT*HWSZ)   // 100352
#define MB    784           // m-blocks (BM=128)
#define NIB   4             // i-blocks (BN=64)
#define GEMMGRID (MB*NIB)   // 3136
#define CPX  (GEMMGRID/8)   // 392 logical blocks per XCD
#define QBLKS 1568          // qsum blocks, 64 m-rows each

// stats slots (floats)
#define S_MN     0          // raw channel sums of relu(x)
#define S_OFFS   256        // u^T @ mn
#define S_DMAX   512
#define S_DMIN   768
#define S_QSUM   1024       // bmean (mean of b over m)
#define S_ROWADD 1280       // mn - sum_k uhs[i][k]*bmean[k]
#define S_MEAN   1536       // mn (normalized channel mean)
#define S_TOTAL  2048

__device__ __forceinline__ ushort f2h(float f){
    _Float16 h = (_Float16)f;               // v_cvt_f16_f32, RNE
    return __builtin_bit_cast(ushort, h);
}
__device__ __forceinline__ float h2f(ushort u){
    return (float)__builtin_bit_cast(_Float16, u);
}
__device__ __forceinline__ void atomicMaxF(float* addr, float v){
    if (v >= 0.f) atomicMax((int*)addr, __float_as_int(v));
    else          atomicMin((unsigned*)addr, (unsigned)__float_as_int(v));
}
__device__ __forceinline__ void atomicMinF(float* addr, float v){
    if (v >= 0.f) atomicMin((int*)addr, __float_as_int(v));
    else          atomicMax((unsigned*)addr, (unsigned)__float_as_int(v));
}
__device__ __forceinline__ void gld_lds16(const void* g, void* l){
    __builtin_amdgcn_global_load_lds((const __attribute__((address_space(1))) void*)g,
                                     (__attribute__((address_space(3))) void*)l, 16, 0, 0);
}
// physical block id -> (bx, iy): each XCD gets a contiguous bx-chunk, iy fastest
__device__ __forceinline__ void xcd_unswizzle(int w, int& bx, int& iy){
    int l = (w & 7)*CPX + (w >> 3);
    bx = l >> 2; iy = l & 3;
}

// ---------------- K_prep: uTh[i][c]=fp16(u[c][i]); blocks 0..7 also init stats ----------------
__global__ void k_prep(const float* __restrict__ u, ushort* __restrict__ uTh,
                       float* __restrict__ stats){
    int i = blockIdx.x, c = threadIdx.x;
    uTh[i*CCH + c] = f2h(u[(size_t)c*CCH + i]);
    if (i < 8){
        int s = i*256 + c;
        float v = 0.f;
        if (s >= S_DMAX && s < S_DMIN)      v = -__builtin_inff();
        else if (s >= S_DMIN && s < S_QSUM) v =  __builtin_inff();
        stats[s] = v;
    }
}

// ---------------- K_trans: xT[m][c] = fp16(relu(x)), + channel sums ----------------
__global__ __launch_bounds__(256) void k_trans(const float* __restrict__ x,
                                               ushort* __restrict__ xT,
                                               float* __restrict__ stats){
    __shared__ ushort tile[64*66];   // [c][hw], pitch 66 ushorts
    __shared__ float csum[64];
    const int hwb = blockIdx.x*64, cb = blockIdx.y*64, n = blockIdx.z;
    const int t = threadIdx.x, lane = t & 63;
    const int hw0 = (t & 15)*4;
    float4 v[4];
    #pragma unroll
    for (int pass = 0; pass < 4; ++pass){
        int c = cb + pass*16 + (t >> 4);
        v[pass] = *(const float4*)&x[((size_t)(n*CCH + c))*HWSZ + hwb + hw0];
    }
    #pragma unroll
    for (int pass = 0; pass < 4; ++pass){
        float a0 = fmaxf(v[pass].x, 0.f), a1 = fmaxf(v[pass].y, 0.f);
        float a2 = fmaxf(v[pass].z, 0.f), a3 = fmaxf(v[pass].w, 0.f);
        int cl = pass*16 + (t >> 4);
        uint p0 = (uint)f2h(a0) | ((uint)f2h(a1) << 16);
        uint p1 = (uint)f2h(a2) | ((uint)f2h(a3) << 16);
        *(uint*)&tile[cl*66 + hw0]     = p0;
        *(uint*)&tile[cl*66 + hw0 + 2] = p1;
        float sv = (a0 + a1) + (a2 + a3);
        #pragma unroll
        for (int o = 1; o < 16; o <<= 1) sv += __shfl_xor(sv, o);
        if ((lane & 15) == 0) csum[cl] = sv;
    }
    __syncthreads();
    {
        int hl = t >> 2, cs = (t & 3)*16;
        short8 o0, o1;
        #pragma unroll
        for (int j = 0; j < 8; ++j) o0[j] = (short)tile[(cs + j)*66 + hl];
        #pragma unroll
        for (int j = 0; j < 8; ++j) o1[j] = (short)tile[(cs + 8 + j)*66 + hl];
        size_t m = (size_t)n*HWSZ + hwb + hl;
        ushort* dst = xT + m*CCH + cb + cs;
        *(short8*)dst       = o0;
        *(short8*)(dst + 8) = o1;
    }
    if (t < 64) atomicAdd(&stats[S_MN + cb + t], csum[t]);
}

// ---------------- K_stats1: offs[i] = u^T@mn (parallel, one block per i); S_MEAN ----------------
__global__ __launch_bounds__(256) void k_stats1(const float* __restrict__ u,
                                                float* __restrict__ stats){
    const int i = blockIdx.x, t = threadIdx.x;
    const float invM = 1.f/(float)MCOLS;
    float mnc  = stats[S_MN + t] * invM;
    float term = u[(size_t)t*CCH + i] * mnc;
    #pragma unroll
    for (int o = 1; o < 64; o <<= 1) term += __shfl_xor(term, o);
    __shared__ float red[4];
    if ((t & 63) == 0) red[t >> 6] = term;
    __syncthreads();
    if (t == 0){
        stats[S_OFFS + i] = red[0] + red[1] + red[2] + red[3];
        stats[S_MEAN + i] = stats[S_MN + i] * invM;
    }
}

// ---------------- K_gemm1: pT[m][i]=fp16(clamp(uT*xb-offs)); minmax partials ----------------
// B-operands preloaded to registers BEFORE the staging barrier: K-loop has zero global loads.
__global__ __launch_bounds__(256) void k_gemm1(const ushort* __restrict__ xT,
                                               const ushort* __restrict__ uTh,
                                               const float* __restrict__ clampVal,
                                               const float* __restrict__ stats,
                                               ushort* __restrict__ pT,
                                               float* __restrict__ pmin,
                                               float* __restrict__ pmax){
    __shared__ ushort sU[64*256];   // 32 KB, XOR-swizzled 16B chunks
    int bx, iy; xcd_unswizzle(blockIdx.x, bx, iy);
    const int m0 = bx*128, i0 = iy*64;
    const int t = threadIdx.x, lane = t & 63, wm = t >> 6;
    const int col = lane & 15, quad = lane >> 4;
    // issue all 16 B loads first (drain during staging + barrier)
    const ushort* xbase = xT + (size_t)(m0 + wm*32 + col)*CCH + quad*8;
    short8 B0[8], B1[8];
    #pragma unroll
    for (int ks = 0; ks < 8; ++ks){
        B0[ks] = *(const short8*)(xbase + ks*32);
        B1[ks] = *(const short8*)(xbase + 16*CCH + ks*32);
    }
    #pragma unroll
    for (int j = 0; j < 8; ++j){
        int cid = j*256 + t;
        int row = cid >> 5, c = cid & 31;
        gld_lds16(uTh + (size_t)(i0+row)*CCH + ((c ^ (row & 7))*8), sU + cid*8);
    }
    floatx4 acc[4][2] = {};
    __syncthreads();
    #pragma unroll
    for (int ks = 0; ks < 8; ++ks){
        half8 b0 = __builtin_bit_cast(half8, B0[ks]);
        half8 b1 = __builtin_bit_cast(half8, B1[ks]);
        #pragma unroll
        for (int fi = 0; fi < 4; ++fi){
            int chunk = (ks*4 + quad) ^ (col & 7);
            half8 a = __builtin_bit_cast(half8, *(const short8*)(sU + (fi*16 + col)*CCH + chunk*8));
            acc[fi][0] = __builtin_amdgcn_mfma_f32_16x16x32_f16(a, b0, acc[fi][0], 0, 0, 0);
            acc[fi][1] = __builtin_amdgcn_mfma_f32_16x16x32_f16(a, b1, acc[fi][1], 0, 0, 0);
        }
    }
    const int R = (iy*MB + bx)*4 + wm;
    #pragma unroll
    for (int fi = 0; fi < 4; ++fi){
        float off[4], cv[4], mnv[4], mxv[4];
        #pragma unroll
        for (int r = 0; r < 4; ++r){
            int ig = i0 + fi*16 + quad*4 + r;
            off[r] = stats[S_OFFS + ig];
            cv[r]  = clampVal[ig];
            mnv[r] =  __builtin_inff();
            mxv[r] = -__builtin_inff();
        }
        #pragma unroll
        for (int fm = 0; fm < 2; ++fm){
            int m = m0 + wm*32 + fm*16 + col;
            ushort pk[4];
            #pragma unroll
            for (int r = 0; r < 4; ++r){
                float v = acc[fi][fm][r] - off[r];
                v = fminf(fmaxf(v, -cv[r]), cv[r]);
                ushort h = f2h(v);
                float vr = h2f(h);
                pk[r] = h;
                mnv[r] = fminf(mnv[r], vr);
                mxv[r] = fmaxf(mxv[r], vr);
            }
            ushort4 q4 = make_ushort4(pk[0], pk[1], pk[2], pk[3]);
            *(ushort4*)(pT + (size_t)m*CCH + i0 + fi*16 + quad*4) = q4;
        }
        #pragma unroll
        for (int r = 0; r < 4; ++r){
            float mn = mnv[r], mx = mxv[r];
            #pragma unroll
            for (int o = 1; o < 16; o <<= 1){
                mn = fminf(mn, __shfl_xor(mn, o));
                mx = fmaxf(mx, __shfl_xor(mx, o));
            }
            if (col == 0){
                int il = fi*16 + quad*4 + r;
                pmin[(size_t)R*64 + il] = mn;
                pmax[(size_t)R*64 + il] = mx;
            }
        }
    }
}

// ---------------- K_mmred: reduce minmax partials -> stats (few atomics) ----------------
__global__ __launch_bounds__(64) void k_mmred(const float* __restrict__ pmin,
                                              const float* __restrict__ pmax,
                                              float* __restrict__ stats){
    const int iy = blockIdx.x, sl = blockIdx.y, il = threadIdx.x;
    float mn = __builtin_inff(), mx = -__builtin_inff();
    const int base = iy*3136 + sl*98;
    for (int r = 0; r < 98; ++r){
        mn = fminf(mn, pmin[(size_t)(base + r)*64 + il]);
        mx = fmaxf(mx, pmax[(size_t)(base + r)*64 + il]);
    }
    atomicMinF(&stats[S_DMIN + iy*64 + il], mn);
    atomicMaxF(&stats[S_DMAX + iy*64 + il], mx);
}

// ---------------- K_qsum: rewrite pT in-place with b; partial b-sums; blocks<256 build uhs ----
// b = n - lv/2 (exact fp16) for quantized channels with ab<=11; else dequantized fp16 value.
__global__ __launch_bounds__(256) void k_qsum(ushort* __restrict__ pT,
                                              const float* __restrict__ u,
                                              const int* __restrict__ abw,
                                              const float* __restrict__ stats,
                                              float* __restrict__ qsump,
                                              ushort* __restrict__ uhs){
    const int t = threadIdx.x, b = blockIdx.x;
    const int ic = (t & 31)*8, ml = t >> 5;
    const int ab = *abw;
    const float lv = (float)(((ab < 17) ? (1 << ab) : 2) - 1);
    const bool cen = (ab < 17) && (ab <= 11);
    const float hl = 0.5f * lv;
    float dmn[8], scl[8], stp[8];
    #pragma unroll
    for (int j = 0; j < 8; ++j){
        float dmax = stats[S_DMAX + ic + j], dmin = stats[S_DMIN + ic + j];
        float rng = dmax - dmin;
        bool doq = (ab < 17) && (rng > 0.f);
        scl[j] = doq ? lv / rng : 0.f;
        stp[j] = doq ? rng / lv : 0.f;
        dmn[j] = dmin;
    }
    float s[8] = {0,0,0,0,0,0,0,0};
    #pragma unroll
    for (int r = 0; r < 8; ++r){
        int m = b*64 + r*8 + ml;
        ushort* prow = pT + (size_t)m*CCH + ic;
        short8 pv = *(const short8*)prow;
        short8 ov;
        #pragma unroll
        for (int j = 0; j < 8; ++j){
            float f = h2f((ushort)pv[j]);
            float bv;
            if (scl[j] > 0.f){
                float n = rintf((f - dmn[j])*scl[j]);
                bv = cen ? (n - hl)
                         : h2f(f2h(fmaf(n, stp[j], dmn[j])));
            } else bv = f;
            ov[j] = (short)f2h(bv);
            s[j] += bv;
        }
        *(short8*)prow = ov;
    }
    __shared__ float red[256*8];
    #pragma unroll
    for (int j = 0; j < 8; ++j) red[(ic + j)*8 + ml] = s[j];
    __syncthreads();
    float tot = 0.f;
    #pragma unroll
    for (int q = 0; q < 8; ++q) tot += red[t*8 + q];
    qsump[(size_t)b*256 + t] = tot;
    // folded prep2: uhs[i][k] = fp16(u[i][k] * stepeff[k])
    if (b < 256){
        float dmax = stats[S_DMAX + t], dmin = stats[S_DMIN + t];
        float rng = dmax - dmin;
        bool cenl = cen && (rng > 0.f);
        float step = cenl ? rng / lv : 1.f;
        uhs[(size_t)b*CCH + t] = f2h(u[(size_t)b*CCH + t] * step);
    }
}

// ---------------- K_stats2a: bmean[k] (one block per k) ----------------
__global__ __launch_bounds__(256) void k_stats2a(const float* __restrict__ qsump,
                                                 float* __restrict__ stats){
    const int k = blockIdx.x, t = threadIdx.x;
    float s = 0.f;
    for (int b = t; b < QBLKS; b += 256) s += qsump[(size_t)b*256 + k];
    #pragma unroll
    for (int o = 1; o < 64; o <<= 1) s += __shfl_xor(s, o);
    __shared__ float red[4];
    if ((t & 63) == 0) red[t >> 6] = s;
    __syncthreads();
    if (t == 0) stats[S_QSUM + k] = (red[0]+red[1]+red[2]+red[3]) * (1.f/(float)MCOLS);
}

// ---------------- K_stats2b: rowadd[i] = mn[i] - sum_k uhs[i][k]*bmean[k] ----------------
__global__ __launch_bounds__(256) void k_stats2b(const ushort* __restrict__ uhs,
                                                 float* __restrict__ stats){
    const int i = blockIdx.x, t = threadIdx.x;
    float term = h2f(uhs[(size_t)i*CCH + t]) * stats[S_QSUM + t];
    #pragma unroll
    for (int o = 1; o < 64; o <<= 1) term += __shfl_xor(term, o);
    __shared__ float red[4];
    if ((t & 63) == 0) red[t >> 6] = term;
    __syncthreads();
    if (t == 0) stats[S_ROWADD + i] = stats[S_MEAN + i] - (red[0]+red[1]+red[2]+red[3]);
}

// ---------------- K_gemm2: pure fp16 GEMM out = uhs*b + rowadd (NCHW fp32) ----------------
// B-operands preloaded to registers before the barrier (same as gemm1).
__global__ __launch_bounds__(256) void k_gemm2(const ushort* __restrict__ pT,
                                               const ushort* __restrict__ uhs,
                                               float* __restrict__ out,
                                               const float* __restrict__ stats){
    __shared__ ushort sU[64*256];   // 32 KB; reused as fp32 staging in epilogue
    int bx, iy; xcd_unswizzle(blockIdx.x, bx, iy);
    const int m0 = bx*128, i0 = iy*64;
    const int t = threadIdx.x, lane = t & 63, wm = t >> 6;
    const int col = lane & 15, quad = lane >> 4;
    const ushort* pbase = pT + (size_t)(m0 + wm*32 + col)*CCH + quad*8;
    short8 B0[8], B1[8];
    #pragma unroll
    for (int ks = 0; ks < 8; ++ks){
        B0[ks] = *(const short8*)(pbase + ks*32);
        B1[ks] = *(const short8*)(pbase + 16*CCH + ks*32);
    }
    #pragma unroll
    for (int j = 0; j < 8; ++j){
        int cid = j*256 + t;
        int row = cid >> 5, c = cid & 31;
        gld_lds16(uhs + (size_t)(i0+row)*CCH + ((c ^ (row & 7))*8), sU + cid*8);
    }
    floatx4 acc[4][2] = {};
    __syncthreads();
    #pragma unroll
    for (int ks = 0; ks < 8; ++ks){
        half8 b0 = __builtin_bit_cast(half8, B0[ks]);
        half8 b1 = __builtin_bit_cast(half8, B1[ks]);
        #pragma unroll
        for (int fi = 0; fi < 4; ++fi){
            int chunk = (ks*4 + quad) ^ (col & 7);
            half8 a = __builtin_bit_cast(half8, *(const short8*)(sU + (fi*16 + col)*CCH + chunk*8));
            acc[fi][0] = __builtin_amdgcn_mfma_f32_16x16x32_f16(a, b0, acc[fi][0], 0, 0, 0);
            acc[fi][1] = __builtin_amdgcn_mfma_f32_16x16x32_f16(a, b1, acc[fi][1], 0, 0, 0);
        }
    }
    // epilogue: stage 32 i-rows at a time through LDS -> 256B contiguous float4 stores
    float* sF = (float*)sU;          // 32 x 132 fp32 = 16.9 KB
    const int rl = t >> 4, c4 = (t & 15)*4;
    #pragma unroll
    for (int p = 0; p < 2; ++p){
        __syncthreads();
        #pragma unroll
        for (int fi2 = 0; fi2 < 2; ++fi2){
            int il = fi2*16 + quad*4;
            #pragma unroll
            for (int fm = 0; fm < 2; ++fm){
                int ml = wm*32 + fm*16 + col;
                #pragma unroll
                for (int r = 0; r < 4; ++r)
                    sF[(il + r)*132 + ml] = acc[p*2 + fi2][fm][r];
            }
        }
        __syncthreads();
        #pragma unroll
        for (int sub = 0; sub < 2; ++sub){
            int il = sub*16 + rl;
            int ig = i0 + p*32 + il;
            float radd = stats[S_ROWADD + ig];
            #pragma unroll
            for (int v = 0; v < 2; ++v){
                int ml = c4 + v*64;
                int m = m0 + ml;
                int n = m / HWSZ, hw = m - n*HWSZ;   // m%4==0, HWSZ%4==0 -> float4 never straddles n
                float4 o;
                o.x = sF[il*132 + ml + 0] + radd;
                o.y = sF[il*132 + ml + 1] + radd;
                o.z = sF[il*132 + ml + 2] + radd;
                o.w = sF[il*132 + ml + 3] + radd;
                *(float4*)&out[((size_t)n*CCH + ig)*HWSZ + hw] = o;
            }
        }
    }
}

extern "C" void kernel_launch(void* const* d_in, const int* in_sizes, int n_in,
                              void* d_out, int out_size, void* d_ws, size_t ws_size,
                              hipStream_t stream){
    const float* x  = (const float*)d_in[0];
    const float* u  = (const float*)d_in[1];
    const float* cv = (const float*)d_in[2];
    const int*   ab = (const int*)d_in[3];
    float* out = (float*)d_out;

    // d_ws: pT + u halves + stats
    ushort* pT   = (ushort*)d_ws;                      // 51.4 MB
    ushort* uTh  = pT + (size_t)MCOLS*CCH;
    ushort* uhs  = uTh + CCH*CCH;
    float*  stats = (float*)(uhs + CCH*CCH);

    // d_out doubles as scratch until k_gemm2 (all dead by then)
    ushort* xT   = (ushort*)d_out;                     // 51.4 MB
    float*  pmin = (float*)((char*)d_out + (size_t)MCOLS*CCH*2);
    float*  pmax = pmin + (size_t)NIB*MB*4*64;         // 12544*64
    float*  qsump = pmax + (size_t)NIB*MB*4*64;        // 1568*256

    k_prep   <<<256, 256, 0, stream>>>(u, uTh, stats);
    k_trans  <<<dim3(49, 4, 32), 256, 0, stream>>>(x, xT, stats);
    k_stats1 <<<256, 256, 0, stream>>>(u, stats);
    k_gemm1  <<<GEMMGRID, 256, 0, stream>>>(xT, uTh, cv, stats, pT, pmin, pmax);
    k_mmred  <<<dim3(NIB, 32), 64, 0, stream>>>(pmin, pmax, stats);
    k_qsum   <<<QBLKS, 256, 0, stream>>>(pT, u, ab, stats, qsump, uhs);
    k_stats2a<<<256, 256, 0, stream>>>(qsump, stats);
    k_stats2b<<<256, 256, 0, stream>>>(uhs, stats);
    k_gemm2  <<<GEMMGRID, 256, 0, stream>>>(pT, uhs, out, stats);
}

// Round 9
// 296.144 us; speedup vs baseline: 1.0490x; 1.0490x over previous
//
#include <hip/hip_runtime.h>
#include <math.h>

typedef unsigned short ushort;
typedef unsigned int uint;
using half8   = __attribute__((ext_vector_type(8))) _Float16;
using short8  = __attribute__((ext_vector_type(8))) short;
using floatx4 = __attribute__((ext_vector_type(4))) float;

#define CCH   256
#define HWSZ  3136
#define NBAT  32
#define MCOLS (NBAT*HWSZ)   // 100352
#define MB    784           // m-blocks (BM=128)
#define NIB   4             // i-blocks (BN=64)
#define GEMMGRID (MB*NIB)   // 3136
#define CPX  (GEMMGRID/8)   // 392 logical blocks per XCD
#define QBLKS 1568          // qsum blocks, 64 m-rows each

// stats slots (floats)
#define S_MN     0          // raw channel sums of relu(x)
#define S_OFFS   256        // u^T @ mn
#define S_DMAX   512
#define S_DMIN   768
#define S_QSUM   1024       // bmean (mean of b over m)
#define S_ROWADD 1280       // mn - sum_k uhs[i][k]*bmean[k]
#define S_MEAN   1536       // mn (normalized channel mean)
#define S_TOTAL  2048

__device__ __forceinline__ ushort f2h(float f){
    _Float16 h = (_Float16)f;               // v_cvt_f16_f32, RNE
    return __builtin_bit_cast(ushort, h);
}
__device__ __forceinline__ float h2f(ushort u){
    return (float)__builtin_bit_cast(_Float16, u);
}
__device__ __forceinline__ void atomicMaxF(float* addr, float v){
    if (v >= 0.f) atomicMax((int*)addr, __float_as_int(v));
    else          atomicMin((unsigned*)addr, (unsigned)__float_as_int(v));
}
__device__ __forceinline__ void atomicMinF(float* addr, float v){
    if (v >= 0.f) atomicMin((int*)addr, __float_as_int(v));
    else          atomicMax((unsigned*)addr, (unsigned)__float_as_int(v));
}
__device__ __forceinline__ void gld_lds16(const void* g, void* l){
    __builtin_amdgcn_global_load_lds((const __attribute__((address_space(1))) void*)g,
                                     (__attribute__((address_space(3))) void*)l, 16, 0, 0);
}
// physical block id -> (bx, iy): each XCD gets a contiguous bx-chunk, iy fastest
__device__ __forceinline__ void xcd_unswizzle(int w, int& bx, int& iy){
    int l = (w & 7)*CPX + (w >> 3);
    bx = l >> 2; iy = l & 3;
}

// ---------------- K_prep: uTh[i][c]=fp16(u[c][i]); blocks 0..7 also init stats ----------------
__global__ void k_prep(const float* __restrict__ u, ushort* __restrict__ uTh,
                       float* __restrict__ stats){
    int i = blockIdx.x, c = threadIdx.x;
    uTh[i*CCH + c] = f2h(u[(size_t)c*CCH + i]);
    if (i < 8){
        int s = i*256 + c;
        float v = 0.f;
        if (s >= S_DMAX && s < S_DMIN)      v = -__builtin_inff();
        else if (s >= S_DMIN && s < S_QSUM) v =  __builtin_inff();
        stats[s] = v;
    }
}

// ---------------- K_trans: xT[m][c] = fp16(relu(x)), + channel sums ----------------
__global__ __launch_bounds__(256) void k_trans(const float* __restrict__ x,
                                               ushort* __restrict__ xT,
                                               float* __restrict__ stats){
    __shared__ ushort tile[64*66];   // [c][hw], pitch 66 ushorts
    __shared__ float csum[64];
    const int hwb = blockIdx.x*64, cb = blockIdx.y*64, n = blockIdx.z;
    const int t = threadIdx.x, lane = t & 63;
    const int hw0 = (t & 15)*4;
    float4 v[4];
    #pragma unroll
    for (int pass = 0; pass < 4; ++pass){
        int c = cb + pass*16 + (t >> 4);
        v[pass] = *(const float4*)&x[((size_t)(n*CCH + c))*HWSZ + hwb + hw0];
    }
    #pragma unroll
    for (int pass = 0; pass < 4; ++pass){
        float a0 = fmaxf(v[pass].x, 0.f), a1 = fmaxf(v[pass].y, 0.f);
        float a2 = fmaxf(v[pass].z, 0.f), a3 = fmaxf(v[pass].w, 0.f);
        int cl = pass*16 + (t >> 4);
        uint p0 = (uint)f2h(a0) | ((uint)f2h(a1) << 16);
        uint p1 = (uint)f2h(a2) | ((uint)f2h(a3) << 16);
        *(uint*)&tile[cl*66 + hw0]     = p0;
        *(uint*)&tile[cl*66 + hw0 + 2] = p1;
        float sv = (a0 + a1) + (a2 + a3);
        #pragma unroll
        for (int o = 1; o < 16; o <<= 1) sv += __shfl_xor(sv, o);
        if ((lane & 15) == 0) csum[cl] = sv;
    }
    __syncthreads();
    {
        int hl = t >> 2, cs = (t & 3)*16;
        short8 o0, o1;
        #pragma unroll
        for (int j = 0; j < 8; ++j) o0[j] = (short)tile[(cs + j)*66 + hl];
        #pragma unroll
        for (int j = 0; j < 8; ++j) o1[j] = (short)tile[(cs + 8 + j)*66 + hl];
        size_t m = (size_t)n*HWSZ + hwb + hl;
        ushort* dst = xT + m*CCH + cb + cs;
        *(short8*)dst       = o0;
        *(short8*)(dst + 8) = o1;
    }
    if (t < 64) atomicAdd(&stats[S_MN + cb + t], csum[t]);
}

// ---------------- K_stats1: offs[i] = u^T@mn (parallel, one block per i); S_MEAN ----------------
__global__ __launch_bounds__(256) void k_stats1(const float* __restrict__ u,
                                                float* __restrict__ stats){
    const int i = blockIdx.x, t = threadIdx.x;
    const float invM = 1.f/(float)MCOLS;
    float mnc  = stats[S_MN + t] * invM;
    float term = u[(size_t)t*CCH + i] * mnc;
    #pragma unroll
    for (int o = 1; o < 64; o <<= 1) term += __shfl_xor(term, o);
    __shared__ float red[4];
    if ((t & 63) == 0) red[t >> 6] = term;
    __syncthreads();
    if (t == 0){
        stats[S_OFFS + i] = red[0] + red[1] + red[2] + red[3];
        stats[S_MEAN + i] = stats[S_MN + i] * invM;
    }
}

// ---------------- K_gemm1: pT[m][i]=fp16(clamp(uT*xb-offs)); minmax -> LDS -> atomics --------
// BN=64, XCD-chunked swizzle; k_mmred eliminated via block-level reduce + per-channel atomics.
__global__ __launch_bounds__(256) void k_gemm1(const ushort* __restrict__ xT,
                                               const ushort* __restrict__ uTh,
                                               const float* __restrict__ clampVal,
                                               float* __restrict__ stats,
                                               ushort* __restrict__ pT){
    __shared__ ushort sU[64*256];   // 32 KB, XOR-swizzled 16B chunks; reused by epilogue reduce
    int bx, iy; xcd_unswizzle(blockIdx.x, bx, iy);
    const int m0 = bx*128, i0 = iy*64;
    const int t = threadIdx.x, lane = t & 63, wm = t >> 6;
    const int col = lane & 15, quad = lane >> 4;
    #pragma unroll
    for (int j = 0; j < 8; ++j){
        int cid = j*256 + t;
        int row = cid >> 5, c = cid & 31;
        gld_lds16(uTh + (size_t)(i0+row)*CCH + ((c ^ (row & 7))*8), sU + cid*8);
    }
    floatx4 acc[4][2] = {};
    __syncthreads();
    const ushort* xbase = xT + (size_t)(m0 + wm*32 + col)*CCH + quad*8;
    #pragma unroll
    for (int ks = 0; ks < 8; ++ks){
        half8 b0 = __builtin_bit_cast(half8, *(const short8*)(xbase + ks*32));
        half8 b1 = __builtin_bit_cast(half8, *(const short8*)(xbase + 16*CCH + ks*32));
        #pragma unroll
        for (int fi = 0; fi < 4; ++fi){
            int chunk = (ks*4 + quad) ^ (col & 7);
            half8 a = __builtin_bit_cast(half8, *(const short8*)(sU + (fi*16 + col)*CCH + chunk*8));
            acc[fi][0] = __builtin_amdgcn_mfma_f32_16x16x32_f16(a, b0, acc[fi][0], 0, 0, 0);
            acc[fi][1] = __builtin_amdgcn_mfma_f32_16x16x32_f16(a, b1, acc[fi][1], 0, 0, 0);
        }
    }
    __syncthreads();                 // sU reads done -> safe to reuse as reduction scratch
    float* red = (float*)sU;         // red[0..255]=min[wm][il], red[256..511]=max[wm][il]
    #pragma unroll
    for (int fi = 0; fi < 4; ++fi){
        float off[4], cv[4], mnv[4], mxv[4];
        #pragma unroll
        for (int r = 0; r < 4; ++r){
            int ig = i0 + fi*16 + quad*4 + r;
            off[r] = stats[S_OFFS + ig];
            cv[r]  = clampVal[ig];
            mnv[r] =  __builtin_inff();
            mxv[r] = -__builtin_inff();
        }
        #pragma unroll
        for (int fm = 0; fm < 2; ++fm){
            int m = m0 + wm*32 + fm*16 + col;
            ushort pk[4];
            #pragma unroll
            for (int r = 0; r < 4; ++r){
                float v = acc[fi][fm][r] - off[r];
                v = fminf(fmaxf(v, -cv[r]), cv[r]);
                ushort h = f2h(v);
                float vr = h2f(h);
                pk[r] = h;
                mnv[r] = fminf(mnv[r], vr);
                mxv[r] = fmaxf(mxv[r], vr);
            }
            ushort4 q4 = make_ushort4(pk[0], pk[1], pk[2], pk[3]);
            *(ushort4*)(pT + (size_t)m*CCH + i0 + fi*16 + quad*4) = q4;
        }
        #pragma unroll
        for (int r = 0; r < 4; ++r){
            float mn = mnv[r], mx = mxv[r];
            #pragma unroll
            for (int o = 1; o < 16; o <<= 1){
                mn = fminf(mn, __shfl_xor(mn, o));
                mx = fmaxf(mx, __shfl_xor(mx, o));
            }
            if (col == 0){
                int il = fi*16 + quad*4 + r;
                red[wm*64 + il]       = mn;
                red[256 + wm*64 + il] = mx;
            }
        }
    }
    __syncthreads();
    if (t < 64){
        float mn = fminf(fminf(red[t], red[64 + t]), fminf(red[128 + t], red[192 + t]));
        float mx = fmaxf(fmaxf(red[256 + t], red[320 + t]), fmaxf(red[384 + t], red[448 + t]));
        atomicMinF(&stats[S_DMIN + i0 + t], mn);
        atomicMaxF(&stats[S_DMAX + i0 + t], mx);
    }
}

// ---------------- K_qsum: rewrite pT in-place with b; partial b-sums; blocks<256 build uhs ----
// b = n - lv/2 (exact fp16) for quantized channels with ab<=11; else dequantized fp16 value.
__global__ __launch_bounds__(256) void k_qsum(ushort* __restrict__ pT,
                                              const float* __restrict__ u,
                                              const int* __restrict__ abw,
                                              const float* __restrict__ stats,
                                              float* __restrict__ qsump,
                                              ushort* __restrict__ uhs){
    const int t = threadIdx.x, b = blockIdx.x;
    const int ic = (t & 31)*8, ml = t >> 5;
    const int ab = *abw;
    const float lv = (float)(((ab < 17) ? (1 << ab) : 2) - 1);
    const bool cen = (ab < 17) && (ab <= 11);
    const float hl = 0.5f * lv;
    float dmn[8], scl[8], stp[8];
    #pragma unroll
    for (int j = 0; j < 8; ++j){
        float dmax = stats[S_DMAX + ic + j], dmin = stats[S_DMIN + ic + j];
        float rng = dmax - dmin;
        bool doq = (ab < 17) && (rng > 0.f);
        scl[j] = doq ? lv / rng : 0.f;
        stp[j] = doq ? rng / lv : 0.f;
        dmn[j] = dmin;
    }
    float s[8] = {0,0,0,0,0,0,0,0};
    #pragma unroll
    for (int r = 0; r < 8; ++r){
        int m = b*64 + r*8 + ml;
        ushort* prow = pT + (size_t)m*CCH + ic;
        short8 pv = *(const short8*)prow;
        short8 ov;
        #pragma unroll
        for (int j = 0; j < 8; ++j){
            float f = h2f((ushort)pv[j]);
            float bv;
            if (scl[j] > 0.f){
                float n = rintf((f - dmn[j])*scl[j]);
                bv = cen ? (n - hl)
                         : h2f(f2h(fmaf(n, stp[j], dmn[j])));
            } else bv = f;
            ov[j] = (short)f2h(bv);
            s[j] += bv;
        }
        *(short8*)prow = ov;
    }
    __shared__ float red[256*8];
    #pragma unroll
    for (int j = 0; j < 8; ++j) red[(ic + j)*8 + ml] = s[j];
    __syncthreads();
    float tot = 0.f;
    #pragma unroll
    for (int q = 0; q < 8; ++q) tot += red[t*8 + q];
    qsump[(size_t)b*256 + t] = tot;
    // folded prep2: uhs[i][k] = fp16(u[i][k] * stepeff[k])
    if (b < 256){
        float dmax = stats[S_DMAX + t], dmin = stats[S_DMIN + t];
        float rng = dmax - dmin;
        bool cenl = cen && (rng > 0.f);
        float step = cenl ? rng / lv : 1.f;
        uhs[(size_t)b*CCH + t] = f2h(u[(size_t)b*CCH + t] * step);
    }
}

// ---------------- K_stats2a: bmean[k] (one block per k) ----------------
__global__ __launch_bounds__(256) void k_stats2a(const float* __restrict__ qsump,
                                                 float* __restrict__ stats){
    const int k = blockIdx.x, t = threadIdx.x;
    float s = 0.f;
    for (int b = t; b < QBLKS; b += 256) s += qsump[(size_t)b*256 + k];
    #pragma unroll
    for (int o = 1; o < 64; o <<= 1) s += __shfl_xor(s, o);
    __shared__ float red[4];
    if ((t & 63) == 0) red[t >> 6] = s;
    __syncthreads();
    if (t == 0) stats[S_QSUM + k] = (red[0]+red[1]+red[2]+red[3]) * (1.f/(float)MCOLS);
}

// ---------------- K_stats2b: rowadd[i] = mn[i] - sum_k uhs[i][k]*bmean[k] ----------------
__global__ __launch_bounds__(256) void k_stats2b(const ushort* __restrict__ uhs,
                                                 float* __restrict__ stats){
    const int i = blockIdx.x, t = threadIdx.x;
    float term = h2f(uhs[(size_t)i*CCH + t]) * stats[S_QSUM + t];
    #pragma unroll
    for (int o = 1; o < 64; o <<= 1) term += __shfl_xor(term, o);
    __shared__ float red[4];
    if ((t & 63) == 0) red[t >> 6] = term;
    __syncthreads();
    if (t == 0) stats[S_ROWADD + i] = stats[S_MEAN + i] - (red[0]+red[1]+red[2]+red[3]);
}

// ---------------- K_gemm2: pure fp16 GEMM out = uhs*b + rowadd (NCHW fp32) ----------------
// BN=64, XCD-chunked swizzle; epilogue staged in 2x 32-row passes
__global__ __launch_bounds__(256) void k_gemm2(const ushort* __restrict__ pT,
                                               const ushort* __restrict__ uhs,
                                               float* __restrict__ out,
                                               const float* __restrict__ stats){
    __shared__ ushort sU[64*256];   // 32 KB; reused as fp32 staging in epilogue
    int bx, iy; xcd_unswizzle(blockIdx.x, bx, iy);
    const int m0 = bx*128, i0 = iy*64;
    const int t = threadIdx.x, lane = t & 63, wm = t >> 6;
    const int col = lane & 15, quad = lane >> 4;
    #pragma unroll
    for (int j = 0; j < 8; ++j){
        int cid = j*256 + t;
        int row = cid >> 5, c = cid & 31;
        gld_lds16(uhs + (size_t)(i0+row)*CCH + ((c ^ (row & 7))*8), sU + cid*8);
    }
    floatx4 acc[4][2] = {};
    __syncthreads();
    const ushort* pbase = pT + (size_t)(m0 + wm*32 + col)*CCH + quad*8;
    #pragma unroll
    for (int ks = 0; ks < 8; ++ks){
        half8 b0 = __builtin_bit_cast(half8, *(const short8*)(pbase + ks*32));
        half8 b1 = __builtin_bit_cast(half8, *(const short8*)(pbase + 16*CCH + ks*32));
        #pragma unroll
        for (int fi = 0; fi < 4; ++fi){
            int chunk = (ks*4 + quad) ^ (col & 7);
            half8 a = __builtin_bit_cast(half8, *(const short8*)(sU + (fi*16 + col)*CCH + chunk*8));
            acc[fi][0] = __builtin_amdgcn_mfma_f32_16x16x32_f16(a, b0, acc[fi][0], 0, 0, 0);
            acc[fi][1] = __builtin_amdgcn_mfma_f32_16x16x32_f16(a, b1, acc[fi][1], 0, 0, 0);
        }
    }
    // epilogue: stage 32 i-rows at a time through LDS -> 256B contiguous float4 stores
    float* sF = (float*)sU;          // 32 x 132 fp32 = 16.9 KB
    const int rl = t >> 4, c4 = (t & 15)*4;
    #pragma unroll
    for (int p = 0; p < 2; ++p){
        __syncthreads();
        #pragma unroll
        for (int fi2 = 0; fi2 < 2; ++fi2){
            int il = fi2*16 + quad*4;
            #pragma unroll
            for (int fm = 0; fm < 2; ++fm){
                int ml = wm*32 + fm*16 + col;
                #pragma unroll
                for (int r = 0; r < 4; ++r)
                    sF[(il + r)*132 + ml] = acc[p*2 + fi2][fm][r];
            }
        }
        __syncthreads();
        #pragma unroll
        for (int sub = 0; sub < 2; ++sub){
            int il = sub*16 + rl;
            int ig = i0 + p*32 + il;
            float radd = stats[S_ROWADD + ig];
            #pragma unroll
            for (int v = 0; v < 2; ++v){
                int ml = c4 + v*64;
                int m = m0 + ml;
                int n = m / HWSZ, hw = m - n*HWSZ;   // m%4==0, HWSZ%4==0 -> float4 never straddles n
                float4 o;
                o.x = sF[il*132 + ml + 0] + radd;
                o.y = sF[il*132 + ml + 1] + radd;
                o.z = sF[il*132 + ml + 2] + radd;
                o.w = sF[il*132 + ml + 3] + radd;
                *(float4*)&out[((size_t)n*CCH + ig)*HWSZ + hw] = o;
            }
        }
    }
}

extern "C" void kernel_launch(void* const* d_in, const int* in_sizes, int n_in,
                              void* d_out, int out_size, void* d_ws, size_t ws_size,
                              hipStream_t stream){
    const float* x  = (const float*)d_in[0];
    const float* u  = (const float*)d_in[1];
    const float* cv = (const float*)d_in[2];
    const int*   ab = (const int*)d_in[3];
    float* out = (float*)d_out;

    // d_ws: pT + u halves + stats
    ushort* pT   = (ushort*)d_ws;                      // 51.4 MB
    ushort* uTh  = pT + (size_t)MCOLS*CCH;
    ushort* uhs  = uTh + CCH*CCH;
    float*  stats = (float*)(uhs + CCH*CCH);

    // d_out doubles as scratch until k_gemm2 (all dead by then)
    ushort* xT   = (ushort*)d_out;                     // 51.4 MB
    float*  qsump = (float*)((char*)d_out + (size_t)MCOLS*CCH*2);   // 1568*256

    k_prep   <<<256, 256, 0, stream>>>(u, uTh, stats);
    k_trans  <<<dim3(49, 4, 32), 256, 0, stream>>>(x, xT, stats);
    k_stats1 <<<256, 256, 0, stream>>>(u, stats);
    k_gemm1  <<<GEMMGRID, 256, 0, stream>>>(xT, uTh, cv, stats, pT);
    k_qsum   <<<QBLKS, 256, 0, stream>>>(pT, u, ab, stats, qsump, uhs);
    k_stats2a<<<256, 256, 0, stream>>>(qsump, stats);
    k_stats2b<<<256, 256, 0, stream>>>(uhs, stats);
    k_gemm2  <<<GEMMGRID, 256, 0, stream>>>(pT, uhs, out, stats);
}